// Round 2
// baseline (460.230 us; speedup 1.0000x reference)
//
#include <hip/hip_runtime.h>
#include <math.h>

// Problem constants (reference: B=8, C=32, O=32, H=256, W=256, K=5, pad=2)
constexpr int IMG_H = 256;
constexpr int IMG_W = 256;
constexpr int NB = 8;
constexpr int NC = 32;
constexpr int NO = 32;
constexpr int PLANE = IMG_H * IMG_W;          // 65536
constexpr int HALF = NB * NC * PLANE;         // 16,777,216 floats (64 MB)

// Kernel A tiling: per-block = one (b, c, 64x64 tile), halo 2.
// Region = 68 rows x 68 cols, stored with row stride 72 floats (288 B) so the
// row-XOR bank swizzle ( byte ^= (row&7)<<4 for byte<256 ) stays in-row and
// bijective. P region at byte 0, V region at byte VOFF of one shared array.
constexpr int ATH = 64;
constexpr int ATW = 64;
constexpr int ARH2 = 68;                      // region rows
constexpr int ARW2 = 72;                      // region row stride (floats)
constexpr int AROWB = ARW2 * 4;               // 288 bytes/row
constexpr int VOFF = ARH2 * AROWB;            // 19584 B: V region offset
constexpr int NQUAD = 18;                     // aligned global quads per row
constexpr int TOTQ = NQUAD * ARH2;            // 1224 quad-tasks
static_assert(TOTQ == 1224, "quad task count");

#define EPSV 1e-20f

typedef float f4 __attribute__((ext_vector_type(4)));
typedef float f2 __attribute__((ext_vector_type(2)));

__device__ __forceinline__ float rcpf_(float x) { return __builtin_amdgcn_rcpf(x); }
__device__ __forceinline__ float softplusf_(float x) {
  return fmaxf(x, 0.0f) + log1pf(expf(-fabsf(x)));
}

// ws layout (floats): [0..31] wp, [32..831] sw (c-major, 25/ch),
// [832..1855] cwT[c][o] (transposed), [1856] sum(sw), [1857] sum(cw)
__global__ void weights_kernel(const float* __restrict__ wp_raw,
                               const float* __restrict__ sw_raw,
                               const float* __restrict__ cw_raw,
                               float* __restrict__ ws) {
  __shared__ float red[256];
  const int t = threadIdx.x;
  if (t < 32) ws[t] = softplusf_(wp_raw[t]);
  float ssum = 0.f;
  for (int i = t; i < NC * 25; i += 256) {
    float v = softplusf_(sw_raw[i]);
    ws[32 + i] = v;
    ssum += v;
  }
  float csum = 0.f;
  for (int i = t; i < NO * NC; i += 256) {
    float v = softplusf_(cw_raw[i]);
    int o = i >> 5, c = i & 31;
    ws[832 + c * NO + o] = v;  // transposed: [c][o]
    csum += v;
  }
  red[t] = ssum; __syncthreads();
  for (int off = 128; off; off >>= 1) { if (t < off) red[t] += red[t + off]; __syncthreads(); }
  const float S_sw = red[0];
  __syncthreads();
  red[t] = csum; __syncthreads();
  for (int off = 128; off; off >>= 1) { if (t < off) red[t] += red[t + off]; __syncthreads(); }
  if (t == 0) { ws[1856] = S_sw; ws[1857] = red[0]; }
}

// Pointwise gradient-propagation math. Requires cdv/cgv pre-zeroed for
// OOB pixels (then Pv = Vv = 0 follows algebraically, no NaN).
__device__ __forceinline__ void pointwise_pv(
    float dv, float cdv, float gxv, float cgv, int gw,
    float wpc, float inv_wp1, float& Pv, float& Vv) {
  // d_left = d with last col zeroed; d_right = d with first col zeroed
  float dl  = (gw == IMG_W - 1) ? 0.f : dv;
  float cdl = (gw == IMG_W - 1) ? 0.f : cdv;
  float dr  = (gw == 0) ? 0.f : dv;
  float cdr = (gw == 0) ? 0.f : cdv;
  float cfd = cdl * cdr;                                      // cgx_from_ds
  float height = (cdl * dl + cdr * dr) * rcpf_(cdl + cdr + EPSV);
  float gfd = (dr - dl) * 0.5f * rcpf_(height + EPSV);        // gx_from_ds
  float den = fmaf(wpc, cgv, cfd);                            // wp*cgx + cgx_from_ds
  float num = fmaf(wpc * cgv, gxv, cfd * gfd);
  float gprop = num * rcpf_(den + EPSV);
  float cprop = den * inv_wp1;
  Pv = cprop;
  Vv = cprop * gprop;
}

// ---------------------------------------------------------------------------
// Kernel A: pointwise gradient-propagation + depthwise 5x5 conv.
// Writes RAW conv sums:  D = conv(P)  into out[0..HALF),
//                        N = conv(V)  into out[HALF..2*HALF).
// (Algebraic identity: U = S*gx_s = (N/Ssw)*D/(D+eps) == N/Ssw to fp32 since
//  D >= ~1e-8 >> 1e-20 always; all scaling folded into kernelB.)
// Staging: aligned float4 global loads (18 quads/row, fully-OOB quads get a
// clamped address + zero mask; partial-OOB quads cannot occur since tile
// origins are 4-aligned). LDS writes/reads use a row-XOR 16B-quad swizzle.
// 512 threads/block, LDS 39,168 B -> 4 blocks/CU = 32 waves/CU (100% occ cap;
// previous 256-thread version capped at 16 waves/CU and measured latency-bound
// with every pipe under 40%).
// ---------------------------------------------------------------------------
__global__ __launch_bounds__(512, 8) void kernelA(
    const float* __restrict__ dp, const float* __restrict__ cdp,
    const float* __restrict__ gxp, const float* __restrict__ cgxp,
    const float* __restrict__ ws, float* __restrict__ out) {
  __shared__ __align__(16) float PVS[2 * ARH2 * ARW2];  // P then V, 39168 B
  char* shb = (char*)PVS;

  const int t = threadIdx.x;
  const int tile = blockIdx.x;           // 16 tiles: 4x4
  const int c = blockIdx.y;
  const int b = blockIdx.z;
  const int h0 = (tile >> 2) * ATH;
  const int w0t = (tile & 3) * ATW;

  const float wpc = ws[c];
  const float inv_wp1 = rcpf_(wpc + 1.0f);
  const int plane = (b * NC + c) * PLANE;

  // ---- stage pointwise P,V over the 68x68 region: 3 rounds of quad-tasks ----
  // task i4 -> region row R = i4/18, quad j = i4%18 covering global cols
  // [w0t + 4j - 4, w0t + 4j), i.e. region cols rc = 4j-2+comp (rc in [0,68)).
  // Rounds 0,1 fully active (i4 <= 1023 < 1224); round 2 tail: 200 threads.
#define STG_LOAD(r) \
  const int i4_##r = t + 512 * (r); \
  const int R_##r = i4_##r / NQUAD; \
  const int jq_##r = i4_##r - NQUAD * R_##r; \
  const int gh_##r = h0 + R_##r - 2; \
  const int ghc_##r = min(max(gh_##r, 0), IMG_H - 1); \
  const int g0_##r = w0t + 4 * jq_##r - 4; \
  const int g0c_##r = min(max(g0_##r, 0), IMG_W - 4); \
  const int gb_##r = plane + ghc_##r * IMG_W + g0c_##r; \
  const f4 d4_##r = *(const f4*)(dp + gb_##r); \
  const f4 c4_##r = *(const f4*)(cdp + gb_##r); \
  const f4 g4_##r = *(const f4*)(gxp + gb_##r); \
  const f4 x4_##r = *(const f4*)(cgxp + gb_##r);

#define STG_PROC(r) \
  { \
    const bool act = (i4_##r < TOTQ); \
    const bool rowv = ((unsigned)gh_##r < (unsigned)IMG_H); \
    float Pq[4], Vq[4]; \
    _Pragma("unroll") \
    for (int q = 0; q < 4; ++q) { \
      const int gw = g0_##r + q; \
      const float m = (rowv & ((unsigned)gw < (unsigned)IMG_W)) ? 1.0f : 0.0f; \
      pointwise_pv(d4_##r[q], c4_##r[q] * m, g4_##r[q], x4_##r[q] * m, gw, \
                   wpc, inv_wp1, Pq[q], Vq[q]); \
    } \
    const int Rb = R_##r * AROWB; \
    const unsigned pm = ((unsigned)(R_##r & 7)) << 4; \
    const int x1 = 16 * jq_##r - 8; \
    const int x2 = 16 * jq_##r; \
    const int o1 = Rb + (int)((unsigned)x1 ^ (x1 < 256 ? pm : 0u)); \
    const int o2 = Rb + (int)((unsigned)x2 ^ (x2 < 256 ? pm : 0u)); \
    if (act & (jq_##r >= 1)) { \
      f2 wp_; wp_[0] = Pq[0]; wp_[1] = Pq[1]; \
      f2 wv_; wv_[0] = Vq[0]; wv_[1] = Vq[1]; \
      *(f2*)(shb + o1) = wp_; \
      *(f2*)(shb + VOFF + o1) = wv_; \
    } \
    if (act & (jq_##r <= 16)) { \
      f2 wp_; wp_[0] = Pq[2]; wp_[1] = Pq[3]; \
      f2 wv_; wv_[0] = Vq[2]; wv_[1] = Vq[3]; \
      *(f2*)(shb + o2) = wp_; \
      *(f2*)(shb + VOFF + o2) = wv_; \
    } \
  }

  STG_LOAD(0)
  STG_LOAD(1)
  STG_LOAD(2)
  STG_PROC(0)
  STG_PROC(1)
  STG_PROC(2)
#undef STG_LOAD
#undef STG_PROC

  // spatial weights for this channel (wave-uniform address -> SGPRs)
  float sww[25];
  #pragma unroll
  for (int k2 = 0; k2 < 25; ++k2) sww[k2] = ws[32 + c * 25 + k2];

  __syncthreads();

  // ---- depthwise 5x5 conv: 512 tasks (64 rows x 8 runs-of-8), 1 per thread ----
  {
    const int tau = t;
    const int row = tau >> 3;
    const int c7 = tau & 7;          // run of 8 px starting at col 8*c7
    const int X0 = 32 * c7;          // row-local byte of first quad of window
    const unsigned keep2 = (c7 == 7) ? 0u : 0x70u;  // X0+32==256 -> no swizzle
    float den8[8], nom8[8];
    #pragma unroll
    for (int q = 0; q < 8; ++q) { den8[q] = 0.f; nom8[q] = 0.f; }
    #pragma unroll
    for (int kr = 0; kr < 5; ++kr) {
      const int R = row + kr;
      const int Rb = R * AROWB;
      const unsigned pm = ((unsigned)(R & 7)) << 4;
      const int o0 = Rb + (int)((unsigned)X0 ^ pm);
      const int o1 = Rb + (int)((unsigned)(X0 + 16) ^ pm);
      const int o2 = Rb + (int)((unsigned)(X0 + 32) ^ (pm & keep2));
      const f4 pa = *(const f4*)(shb + o0);
      const f4 pb = *(const f4*)(shb + o1);
      const f4 pc = *(const f4*)(shb + o2);
      const f4 va = *(const f4*)(shb + VOFF + o0);
      const f4 vb = *(const f4*)(shb + VOFF + o1);
      const f4 vc = *(const f4*)(shb + VOFF + o2);
      float pr[12] = {pa[0], pa[1], pa[2], pa[3], pb[0], pb[1], pb[2], pb[3],
                      pc[0], pc[1], pc[2], pc[3]};
      float vr[12] = {va[0], va[1], va[2], va[3], vb[0], vb[1], vb[2], vb[3],
                      vc[0], vc[1], vc[2], vc[3]};
      #pragma unroll
      for (int kc = 0; kc < 5; ++kc) {
        float wv = sww[kr * 5 + kc];
        #pragma unroll
        for (int q = 0; q < 8; ++q) {
          den8[q] = fmaf(wv, pr[kc + q], den8[q]);
          nom8[q] = fmaf(wv, vr[kc + q], nom8[q]);
        }
      }
    }
    // write raw conv sums: D -> first half, N -> second half
    const int gidx = plane + (h0 + row) * IMG_W + w0t + 8 * c7;  // 32B aligned
    float4* sg = (float4*)&out[gidx];
    float4* ug = (float4*)&out[HALF + gidx];
    sg[0] = make_float4(den8[0], den8[1], den8[2], den8[3]);
    sg[1] = make_float4(den8[4], den8[5], den8[6], den8[7]);
    ug[0] = make_float4(nom8[0], nom8[1], nom8[2], nom8[3]);
    ug[1] = make_float4(nom8[4], nom8[5], nom8[6], nom8[7]);
  }
}

// ---------------------------------------------------------------------------
// Kernel B: 1x1 channel normalized conv, in-place on d_out.
// Reads D (first half) and N (second half) for its 256 block-private pixels,
// then overwrites them with gx_out / cgx_out. Barrier between reads & writes.
// Exact compensation for kernelA writing raw D,N:
//   gx_out  = (Σ cw·N) / (Σ cw·D + EPS·Ssw) + bias
//   cgx_out = (Σ cw·D) · (1/Ssw) · (1/Scw)
// ---------------------------------------------------------------------------
__global__ __launch_bounds__(256, 4) void kernelB(
    float* __restrict__ out, const float* __restrict__ ws,
    const float* __restrict__ bias) {
  __shared__ __align__(16) float wlds[NC * NO];  // cwT [c][o]
  __shared__ float blds[NO];

  const int t = threadIdx.x;
  ((float4*)wlds)[t] = ((const float4*)(ws + 832))[t];  // 256*4 = 1024 floats
  if (t < NO) blds[t] = bias[t];
  const float Ssw = ws[1856];
  const float Scw = ws[1857];
  const float epsS = EPSV * Ssw;
  const float scale = rcpf_(Ssw) * rcpf_(Scw);
  __syncthreads();

  const int og = __builtin_amdgcn_readfirstlane(t >> 6);  // wave-uniform
  const int lane = t & 63;
  const int b = blockIdx.y;
  const int hw = blockIdx.x * 256 + lane * 4;
  const int idx0 = b * NC * PLANE + hw;

  float4 accn[8], accd[8];
  #pragma unroll
  for (int o = 0; o < 8; ++o) {
    accn[o] = make_float4(0.f, 0.f, 0.f, 0.f);
    accd[o] = make_float4(0.f, 0.f, 0.f, 0.f);
  }

  #pragma unroll 8
  for (int c = 0; c < NC; ++c) {
    const float4 s4 = *(const float4*)&out[idx0 + c * PLANE];
    const float4 u4 = *(const float4*)&out[HALF + idx0 + c * PLANE];
    const float* w8 = &wlds[c * NO + og * 8];
    #pragma unroll
    for (int o = 0; o < 8; ++o) {
      float wv = w8[o];
      accn[o].x = fmaf(wv, u4.x, accn[o].x);
      accn[o].y = fmaf(wv, u4.y, accn[o].y);
      accn[o].z = fmaf(wv, u4.z, accn[o].z);
      accn[o].w = fmaf(wv, u4.w, accn[o].w);
      accd[o].x = fmaf(wv, s4.x, accd[o].x);
      accd[o].y = fmaf(wv, s4.y, accd[o].y);
      accd[o].z = fmaf(wv, s4.z, accd[o].z);
      accd[o].w = fmaf(wv, s4.w, accd[o].w);
    }
  }

  __syncthreads();  // all reads in block done before any in-place write

  #pragma unroll
  for (int o = 0; o < 8; ++o) {
    int oo = og * 8 + o;
    float bv = blds[oo];
    float4 dn = accd[o];
    float4 g, cg;
    g.x = fmaf(accn[o].x, rcpf_(dn.x + epsS), bv);
    g.y = fmaf(accn[o].y, rcpf_(dn.y + epsS), bv);
    g.z = fmaf(accn[o].z, rcpf_(dn.z + epsS), bv);
    g.w = fmaf(accn[o].w, rcpf_(dn.w + epsS), bv);
    cg.x = dn.x * scale; cg.y = dn.y * scale;
    cg.z = dn.z * scale; cg.w = dn.w * scale;
    int oidx = (b * NO + oo) * PLANE + hw;
    *(float4*)&out[oidx] = g;
    *(float4*)&out[HALF + oidx] = cg;
  }
}

extern "C" void kernel_launch(void* const* d_in, const int* in_sizes, int n_in,
                              void* d_out, int out_size, void* d_ws, size_t ws_size,
                              hipStream_t stream) {
  const float* dp   = (const float*)d_in[0];
  const float* cdp  = (const float*)d_in[1];
  const float* gxp  = (const float*)d_in[2];
  const float* cgxp = (const float*)d_in[3];
  const float* wp   = (const float*)d_in[4];
  const float* sw   = (const float*)d_in[5];
  const float* cw   = (const float*)d_in[6];
  const float* bias = (const float*)d_in[7];
  float* out = (float*)d_out;
  float* ws  = (float*)d_ws;

  weights_kernel<<<1, 256, 0, stream>>>(wp, sw, cw, ws);
  kernelA<<<dim3(16, NC, NB), 512, 0, stream>>>(dp, cdp, gxp, cgxp, ws, out);
  kernelB<<<dim3(PLANE / 256, NB), 256, 0, stream>>>(out, ws, bias);
}

// Round 3
// 418.641 us; speedup vs baseline: 1.0993x; 1.0993x over previous
//
#include <hip/hip_runtime.h>
#include <math.h>

// Problem constants (reference: B=8, C=32, O=32, H=256, W=256, K=5, pad=2)
constexpr int IMG_H = 256;
constexpr int IMG_W = 256;
constexpr int NB = 8;
constexpr int NC = 32;
constexpr int NO = 32;
constexpr int PLANE = IMG_H * IMG_W;          // 65536
constexpr int HALF = NB * NC * PLANE;         // 16,777,216 floats (64 MB)

// Kernel A tiling: per-block = one (b, c, 64x64 tile), halo 2.
// Region = 68 rows x 68 cols, stored with row stride 72 floats (288 B) so the
// row-XOR bank swizzle ( byte ^= (row&7)<<4 for byte<256 ) stays in-row and
// bijective. P region at byte 0, V region at byte VOFF of one shared array.
constexpr int ATH = 64;
constexpr int ATW = 64;
constexpr int ARH2 = 68;                      // region rows
constexpr int ARW2 = 72;                      // region row stride (floats)
constexpr int AROWB = ARW2 * 4;               // 288 bytes/row
constexpr int VOFF = ARH2 * AROWB;            // 19584 B: V region offset
constexpr int NQUAD = 18;                     // aligned global quads per row
constexpr int TOTQ = NQUAD * ARH2;            // 1224 quad-tasks
constexpr int NT_A = 384;                     // 6 waves/block
static_assert(TOTQ == 1224, "quad task count");

#define EPSV 1e-20f

typedef float f4 __attribute__((ext_vector_type(4)));
typedef float f2 __attribute__((ext_vector_type(2)));

__device__ __forceinline__ float rcpf_(float x) { return __builtin_amdgcn_rcpf(x); }
__device__ __forceinline__ float softplusf_(float x) {
  return fmaxf(x, 0.0f) + log1pf(expf(-fabsf(x)));
}

// ws layout (floats): [0..31] wp, [32..831] sw (c-major, 25/ch),
// [832..1855] cwT[c][o] (transposed), [1856] sum(sw), [1857] sum(cw)
__global__ void weights_kernel(const float* __restrict__ wp_raw,
                               const float* __restrict__ sw_raw,
                               const float* __restrict__ cw_raw,
                               float* __restrict__ ws) {
  __shared__ float red[256];
  const int t = threadIdx.x;
  if (t < 32) ws[t] = softplusf_(wp_raw[t]);
  float ssum = 0.f;
  for (int i = t; i < NC * 25; i += 256) {
    float v = softplusf_(sw_raw[i]);
    ws[32 + i] = v;
    ssum += v;
  }
  float csum = 0.f;
  for (int i = t; i < NO * NC; i += 256) {
    float v = softplusf_(cw_raw[i]);
    int o = i >> 5, c = i & 31;
    ws[832 + c * NO + o] = v;  // transposed: [c][o]
    csum += v;
  }
  red[t] = ssum; __syncthreads();
  for (int off = 128; off; off >>= 1) { if (t < off) red[t] += red[t + off]; __syncthreads(); }
  const float S_sw = red[0];
  __syncthreads();
  red[t] = csum; __syncthreads();
  for (int off = 128; off; off >>= 1) { if (t < off) red[t] += red[t + off]; __syncthreads(); }
  if (t == 0) { ws[1856] = S_sw; ws[1857] = red[0]; }
}

// Pointwise gradient-propagation math. Requires cdv/cgv pre-zeroed for
// OOB pixels (then Pv = Vv = 0 follows algebraically, no NaN).
__device__ __forceinline__ void pointwise_pv(
    float dv, float cdv, float gxv, float cgv, int gw,
    float wpc, float inv_wp1, float& Pv, float& Vv) {
  // d_left = d with last col zeroed; d_right = d with first col zeroed
  float dl  = (gw == IMG_W - 1) ? 0.f : dv;
  float cdl = (gw == IMG_W - 1) ? 0.f : cdv;
  float dr  = (gw == 0) ? 0.f : dv;
  float cdr = (gw == 0) ? 0.f : cdv;
  float cfd = cdl * cdr;                                      // cgx_from_ds
  float height = (cdl * dl + cdr * dr) * rcpf_(cdl + cdr + EPSV);
  float gfd = (dr - dl) * 0.5f * rcpf_(height + EPSV);        // gx_from_ds
  float den = fmaf(wpc, cgv, cfd);                            // wp*cgx + cgx_from_ds
  float num = fmaf(wpc * cgv, gxv, cfd * gfd);
  float gprop = num * rcpf_(den + EPSV);
  float cprop = den * inv_wp1;
  Pv = cprop;
  Vv = cprop * gprop;
}

// ---------------------------------------------------------------------------
// Kernel A: pointwise gradient-propagation + depthwise 5x5 conv.
// Writes RAW conv sums:  D = conv(P)  into out[0..HALF),
//                        N = conv(V)  into out[HALF..2*HALF).
// (Algebraic identity: U = S*gx_s = (N/Ssw)*D/(D+eps) == N/Ssw to fp32 since
//  D >= ~1e-8 >> 1e-20 always; all scaling folded into kernelB.)
// Staging: aligned float4 global loads (18 quads/row, fully-OOB quads get a
// clamped address + zero mask). LDS row-XOR 16B-quad swizzle on write & read.
//
// Occupancy history: 256 thr -> 16 waves/CU (50% cap), latency-bound at 132us.
// 512 thr @ launch_bounds(512,8) -> VGPR squeezed to 32, staging pipeline
// (12 f4 in flight) spilled to scratch: FETCH +102MB, WRITE +165MB, 170us.
// 384 thr @ launch_bounds(384,6): 4 blocks/CU (LDS 39.2KB) x 6 waves =
// 24 waves/CU (75% cap), VGPR budget 85 > the ~52 this pipeline needs.
// ---------------------------------------------------------------------------
__global__ __launch_bounds__(NT_A, 6) void kernelA(
    const float* __restrict__ dp, const float* __restrict__ cdp,
    const float* __restrict__ gxp, const float* __restrict__ cgxp,
    const float* __restrict__ ws, float* __restrict__ out) {
  __shared__ __align__(16) float PVS[2 * ARH2 * ARW2];  // P then V, 39168 B
  char* shb = (char*)PVS;

  const int t = threadIdx.x;
  const int tile = blockIdx.x;           // 16 tiles: 4x4
  const int c = blockIdx.y;
  const int b = blockIdx.z;
  const int h0 = (tile >> 2) * ATH;
  const int w0t = (tile & 3) * ATW;

  const float wpc = ws[c];
  const float inv_wp1 = rcpf_(wpc + 1.0f);
  const int plane = (b * NC + c) * PLANE;

  // ---- stage pointwise P,V over the 68x68 region: 4 rounds of quad-tasks ----
  // task i4 -> region row R = i4/18, quad j = i4%18 covering global cols
  // [w0t + 4j - 4, w0t + 4j). Rounds 0-2 fully active (<=1151); round 3:
  // tasks 1152..1223 (72 threads), others clamped+masked.
#define STG_LOAD(r) \
  const int i4r_##r = t + NT_A * (r); \
  const int i4_##r = min(i4r_##r, TOTQ - 1); \
  const int R_##r = i4_##r / NQUAD; \
  const int jq_##r = i4_##r - NQUAD * R_##r; \
  const int gh_##r = h0 + R_##r - 2; \
  const int ghc_##r = min(max(gh_##r, 0), IMG_H - 1); \
  const int g0_##r = w0t + 4 * jq_##r - 4; \
  const int g0c_##r = min(max(g0_##r, 0), IMG_W - 4); \
  const int gb_##r = plane + ghc_##r * IMG_W + g0c_##r; \
  const f4 d4_##r = *(const f4*)(dp + gb_##r); \
  const f4 c4_##r = *(const f4*)(cdp + gb_##r); \
  const f4 g4_##r = *(const f4*)(gxp + gb_##r); \
  const f4 x4_##r = *(const f4*)(cgxp + gb_##r);

#define STG_PROC(r) \
  { \
    const bool act = (i4r_##r < TOTQ); \
    const bool rowv = ((unsigned)gh_##r < (unsigned)IMG_H); \
    float Pq[4], Vq[4]; \
    _Pragma("unroll") \
    for (int q = 0; q < 4; ++q) { \
      const int gw = g0_##r + q; \
      const float m = (rowv & ((unsigned)gw < (unsigned)IMG_W)) ? 1.0f : 0.0f; \
      pointwise_pv(d4_##r[q], c4_##r[q] * m, g4_##r[q], x4_##r[q] * m, gw, \
                   wpc, inv_wp1, Pq[q], Vq[q]); \
    } \
    const int Rb = R_##r * AROWB; \
    const unsigned pm = ((unsigned)(R_##r & 7)) << 4; \
    const int x1 = 16 * jq_##r - 8; \
    const int x2 = 16 * jq_##r; \
    const int o1 = Rb + (int)((unsigned)x1 ^ (x1 < 256 ? pm : 0u)); \
    const int o2 = Rb + (int)((unsigned)x2 ^ (x2 < 256 ? pm : 0u)); \
    if (act & (jq_##r >= 1)) { \
      f2 wp_; wp_[0] = Pq[0]; wp_[1] = Pq[1]; \
      f2 wv_; wv_[0] = Vq[0]; wv_[1] = Vq[1]; \
      *(f2*)(shb + o1) = wp_; \
      *(f2*)(shb + VOFF + o1) = wv_; \
    } \
    if (act & (jq_##r <= 16)) { \
      f2 wp_; wp_[0] = Pq[2]; wp_[1] = Pq[3]; \
      f2 wv_; wv_[0] = Vq[2]; wv_[1] = Vq[3]; \
      *(f2*)(shb + o2) = wp_; \
      *(f2*)(shb + VOFF + o2) = wv_; \
    } \
  }

  STG_LOAD(0)
  STG_LOAD(1)
  STG_LOAD(2)
  STG_PROC(0)
  STG_LOAD(3)
  STG_PROC(1)
  STG_PROC(2)
  STG_PROC(3)
#undef STG_LOAD
#undef STG_PROC

  // spatial weights for this channel (wave-uniform address -> SGPRs)
  float sww[25];
  #pragma unroll
  for (int k2 = 0; k2 < 25; ++k2) sww[k2] = ws[32 + c * 25 + k2];

  __syncthreads();

  // ---- depthwise 5x5 conv: 512 tasks (64 rows x 8 runs-of-8) ----
  // 384 threads: all do task t; t<128 also do task t+384.
  #pragma unroll 1
  for (int jj = 0; jj < 2; ++jj) {
    const int tau = t + jj * NT_A;
    if (tau >= 512) break;
    const int row = tau >> 3;
    const int c7 = tau & 7;          // run of 8 px starting at col 8*c7
    const int X0 = 32 * c7;          // row-local byte of first quad of window
    const unsigned keep2 = (c7 == 7) ? 0u : 0x70u;  // X0+32==256 -> no swizzle
    float den8[8], nom8[8];
    #pragma unroll
    for (int q = 0; q < 8; ++q) { den8[q] = 0.f; nom8[q] = 0.f; }
    #pragma unroll
    for (int kr = 0; kr < 5; ++kr) {
      const int R = row + kr;
      const int Rb = R * AROWB;
      const unsigned pm = ((unsigned)(R & 7)) << 4;
      const int o0 = Rb + (int)((unsigned)X0 ^ pm);
      const int o1 = Rb + (int)((unsigned)(X0 + 16) ^ pm);
      const int o2 = Rb + (int)((unsigned)(X0 + 32) ^ (pm & keep2));
      const f4 pa = *(const f4*)(shb + o0);
      const f4 pb = *(const f4*)(shb + o1);
      const f4 pc = *(const f4*)(shb + o2);
      const f4 va = *(const f4*)(shb + VOFF + o0);
      const f4 vb = *(const f4*)(shb + VOFF + o1);
      const f4 vc = *(const f4*)(shb + VOFF + o2);
      float pr[12] = {pa[0], pa[1], pa[2], pa[3], pb[0], pb[1], pb[2], pb[3],
                      pc[0], pc[1], pc[2], pc[3]};
      float vr[12] = {va[0], va[1], va[2], va[3], vb[0], vb[1], vb[2], vb[3],
                      vc[0], vc[1], vc[2], vc[3]};
      #pragma unroll
      for (int kc = 0; kc < 5; ++kc) {
        float wv = sww[kr * 5 + kc];
        #pragma unroll
        for (int q = 0; q < 8; ++q) {
          den8[q] = fmaf(wv, pr[kc + q], den8[q]);
          nom8[q] = fmaf(wv, vr[kc + q], nom8[q]);
        }
      }
    }
    // write raw conv sums: D -> first half, N -> second half
    const int gidx = plane + (h0 + row) * IMG_W + w0t + 8 * c7;  // 32B aligned
    float4* sg = (float4*)&out[gidx];
    float4* ug = (float4*)&out[HALF + gidx];
    sg[0] = make_float4(den8[0], den8[1], den8[2], den8[3]);
    sg[1] = make_float4(den8[4], den8[5], den8[6], den8[7]);
    ug[0] = make_float4(nom8[0], nom8[1], nom8[2], nom8[3]);
    ug[1] = make_float4(nom8[4], nom8[5], nom8[6], nom8[7]);
  }
}

// ---------------------------------------------------------------------------
// Kernel B: 1x1 channel normalized conv, in-place on d_out.
// Reads D (first half) and N (second half) for its 256 block-private pixels,
// then overwrites them with gx_out / cgx_out. Barrier between reads & writes.
// Exact compensation for kernelA writing raw D,N:
//   gx_out  = (Σ cw·N) / (Σ cw·D + EPS·Ssw) + bias
//   cgx_out = (Σ cw·D) · (1/Ssw) · (1/Scw)
// ---------------------------------------------------------------------------
__global__ __launch_bounds__(256, 4) void kernelB(
    float* __restrict__ out, const float* __restrict__ ws,
    const float* __restrict__ bias) {
  __shared__ __align__(16) float wlds[NC * NO];  // cwT [c][o]
  __shared__ float blds[NO];

  const int t = threadIdx.x;
  ((float4*)wlds)[t] = ((const float4*)(ws + 832))[t];  // 256*4 = 1024 floats
  if (t < NO) blds[t] = bias[t];
  const float Ssw = ws[1856];
  const float Scw = ws[1857];
  const float epsS = EPSV * Ssw;
  const float scale = rcpf_(Ssw) * rcpf_(Scw);
  __syncthreads();

  const int og = __builtin_amdgcn_readfirstlane(t >> 6);  // wave-uniform
  const int lane = t & 63;
  const int b = blockIdx.y;
  const int hw = blockIdx.x * 256 + lane * 4;
  const int idx0 = b * NC * PLANE + hw;

  float4 accn[8], accd[8];
  #pragma unroll
  for (int o = 0; o < 8; ++o) {
    accn[o] = make_float4(0.f, 0.f, 0.f, 0.f);
    accd[o] = make_float4(0.f, 0.f, 0.f, 0.f);
  }

  #pragma unroll 8
  for (int c = 0; c < NC; ++c) {
    const float4 s4 = *(const float4*)&out[idx0 + c * PLANE];
    const float4 u4 = *(const float4*)&out[HALF + idx0 + c * PLANE];
    const float* w8 = &wlds[c * NO + og * 8];
    #pragma unroll
    for (int o = 0; o < 8; ++o) {
      float wv = w8[o];
      accn[o].x = fmaf(wv, u4.x, accn[o].x);
      accn[o].y = fmaf(wv, u4.y, accn[o].y);
      accn[o].z = fmaf(wv, u4.z, accn[o].z);
      accn[o].w = fmaf(wv, u4.w, accn[o].w);
      accd[o].x = fmaf(wv, s4.x, accd[o].x);
      accd[o].y = fmaf(wv, s4.y, accd[o].y);
      accd[o].z = fmaf(wv, s4.z, accd[o].z);
      accd[o].w = fmaf(wv, s4.w, accd[o].w);
    }
  }

  __syncthreads();  // all reads in block done before any in-place write

  #pragma unroll
  for (int o = 0; o < 8; ++o) {
    int oo = og * 8 + o;
    float bv = blds[oo];
    float4 dn = accd[o];
    float4 g, cg;
    g.x = fmaf(accn[o].x, rcpf_(dn.x + epsS), bv);
    g.y = fmaf(accn[o].y, rcpf_(dn.y + epsS), bv);
    g.z = fmaf(accn[o].z, rcpf_(dn.z + epsS), bv);
    g.w = fmaf(accn[o].w, rcpf_(dn.w + epsS), bv);
    cg.x = dn.x * scale; cg.y = dn.y * scale;
    cg.z = dn.z * scale; cg.w = dn.w * scale;
    int oidx = (b * NO + oo) * PLANE + hw;
    *(float4*)&out[oidx] = g;
    *(float4*)&out[HALF + oidx] = cg;
  }
}

extern "C" void kernel_launch(void* const* d_in, const int* in_sizes, int n_in,
                              void* d_out, int out_size, void* d_ws, size_t ws_size,
                              hipStream_t stream) {
  const float* dp   = (const float*)d_in[0];
  const float* cdp  = (const float*)d_in[1];
  const float* gxp  = (const float*)d_in[2];
  const float* cgxp = (const float*)d_in[3];
  const float* wp   = (const float*)d_in[4];
  const float* sw   = (const float*)d_in[5];
  const float* cw   = (const float*)d_in[6];
  const float* bias = (const float*)d_in[7];
  float* out = (float*)d_out;
  float* ws  = (float*)d_ws;

  weights_kernel<<<1, 256, 0, stream>>>(wp, sw, cw, ws);
  kernelA<<<dim3(16, NC, NB), NT_A, 0, stream>>>(dp, cdp, gxp, cgxp, ws, out);
  kernelB<<<dim3(PLANE / 256, NB), 256, 0, stream>>>(out, ws, bias);
}

// Round 4
// 414.848 us; speedup vs baseline: 1.1094x; 1.0091x over previous
//
#include <hip/hip_runtime.h>
#include <math.h>

// Problem constants (reference: B=8, C=32, O=32, H=256, W=256, K=5, pad=2)
constexpr int IMG_H = 256;
constexpr int IMG_W = 256;
constexpr int NB = 8;
constexpr int NC = 32;
constexpr int NO = 32;
constexpr int PLANE = IMG_H * IMG_W;          // 65536
constexpr int HALF = NB * NC * PLANE;         // 16,777,216 floats (64 MB)

// Kernel A tiling: per-block = one (b, c, 64x64 tile), halo 2.
// Region = 68 rows x 68 cols, stored with row stride 72 floats (288 B) so the
// row-XOR bank swizzle ( byte ^= (row&7)<<4 for byte<256 ) stays in-row and
// bijective. P region at byte 0, V region at byte VOFF of one shared array.
constexpr int ATH = 64;
constexpr int ATW = 64;
constexpr int ARH2 = 68;                      // region rows
constexpr int ARW2 = 72;                      // region row stride (floats)
constexpr int AROWB = ARW2 * 4;               // 288 bytes/row
constexpr int VOFF = ARH2 * AROWB;            // 19584 B: V region offset
constexpr int NQUAD = 18;                     // aligned global quads per row
constexpr int TOTQ = NQUAD * ARH2;            // 1224 quad-tasks
constexpr int NT_A = 512;                     // 8 waves/block
static_assert(TOTQ == 1224, "quad task count");

#define EPSV 1e-20f

typedef float f4 __attribute__((ext_vector_type(4)));
typedef float f2 __attribute__((ext_vector_type(2)));

__device__ __forceinline__ float rcpf_(float x) { return __builtin_amdgcn_rcpf(x); }
__device__ __forceinline__ float softplusf_(float x) {
  return fmaxf(x, 0.0f) + log1pf(expf(-fabsf(x)));
}

// ws layout (floats): [0..31] wp, [32..831] sw (c-major, 25/ch),
// [832..1855] cwT[c][o] (transposed), [1856] sum(sw), [1857] sum(cw)
__global__ void weights_kernel(const float* __restrict__ wp_raw,
                               const float* __restrict__ sw_raw,
                               const float* __restrict__ cw_raw,
                               float* __restrict__ ws) {
  __shared__ float red[256];
  const int t = threadIdx.x;
  if (t < 32) ws[t] = softplusf_(wp_raw[t]);
  float ssum = 0.f;
  for (int i = t; i < NC * 25; i += 256) {
    float v = softplusf_(sw_raw[i]);
    ws[32 + i] = v;
    ssum += v;
  }
  float csum = 0.f;
  for (int i = t; i < NO * NC; i += 256) {
    float v = softplusf_(cw_raw[i]);
    int o = i >> 5, c = i & 31;
    ws[832 + c * NO + o] = v;  // transposed: [c][o]
    csum += v;
  }
  red[t] = ssum; __syncthreads();
  for (int off = 128; off; off >>= 1) { if (t < off) red[t] += red[t + off]; __syncthreads(); }
  const float S_sw = red[0];
  __syncthreads();
  red[t] = csum; __syncthreads();
  for (int off = 128; off; off >>= 1) { if (t < off) red[t] += red[t + off]; __syncthreads(); }
  if (t == 0) { ws[1856] = S_sw; ws[1857] = red[0]; }
}

// Pointwise gradient-propagation math. Requires cdv/cgv pre-zeroed for
// OOB pixels (then Pv = Vv = 0 follows algebraically, no NaN).
__device__ __forceinline__ void pointwise_pv(
    float dv, float cdv, float gxv, float cgv, int gw,
    float wpc, float inv_wp1, float& Pv, float& Vv) {
  // d_left = d with last col zeroed; d_right = d with first col zeroed
  float dl  = (gw == IMG_W - 1) ? 0.f : dv;
  float cdl = (gw == IMG_W - 1) ? 0.f : cdv;
  float dr  = (gw == 0) ? 0.f : dv;
  float cdr = (gw == 0) ? 0.f : cdv;
  float cfd = cdl * cdr;                                      // cgx_from_ds
  float height = (cdl * dl + cdr * dr) * rcpf_(cdl + cdr + EPSV);
  float gfd = (dr - dl) * 0.5f * rcpf_(height + EPSV);        // gx_from_ds
  float den = fmaf(wpc, cgv, cfd);                            // wp*cgx + cgx_from_ds
  float num = fmaf(wpc * cgv, gxv, cfd * gfd);
  float gprop = num * rcpf_(den + EPSV);
  float cprop = den * inv_wp1;
  Pv = cprop;
  Vv = cprop * gprop;
}

// ---------------------------------------------------------------------------
// Kernel A: pointwise gradient-propagation + depthwise 5x5 conv.
// Writes RAW conv sums:  D = conv(P)  into out[0..HALF),
//                        N = conv(V)  into out[HALF..2*HALF).
// (Algebraic identity: U = S*gx_s = (N/Ssw)*D/(D+eps) == N/Ssw to fp32 since
//  D >= ~1e-8 >> 1e-20 always; all scaling folded into kernelB.)
// Staging: aligned float4 global loads (18 quads/row, fully-OOB quads get a
// clamped address + zero mask). LDS row-XOR 16B-quad swizzle on write & read.
//
// Occupancy history (measured):
//   256 thr (4 w/blk): occ 39%, 2.9 TB/s, 132us  — latency-bound
//   512 thr @ bounds(512,8): VGPR pinned 32 -> spills (+270MB HBM), but
//       occ 77% and 3.9 TB/s total throughput, 170us — residency lever works
//   384 thr @ bounds(384,6): VGPR 40 clean, but occ stuck 40%, 132us —
//       odd-wave blocks pack poorly
// This version: 512 thr @ bounds(512,6) — VGPR budget 85, natural alloc
// ~40-52 <= 64 keeps 8 waves/EU legal at runtime; LDS 39.2KB -> 4 blocks/CU
// -> 32 waves/CU cap with no register squeeze.
// ---------------------------------------------------------------------------
__global__ __launch_bounds__(NT_A, 6) void kernelA(
    const float* __restrict__ dp, const float* __restrict__ cdp,
    const float* __restrict__ gxp, const float* __restrict__ cgxp,
    const float* __restrict__ ws, float* __restrict__ out) {
  __shared__ __align__(16) float PVS[2 * ARH2 * ARW2];  // P then V, 39168 B
  char* shb = (char*)PVS;

  const int t = threadIdx.x;
  const int tile = blockIdx.x;           // 16 tiles: 4x4
  const int c = blockIdx.y;
  const int b = blockIdx.z;
  const int h0 = (tile >> 2) * ATH;
  const int w0t = (tile & 3) * ATW;

  const float wpc = ws[c];
  const float inv_wp1 = rcpf_(wpc + 1.0f);
  const int plane = (b * NC + c) * PLANE;

  // ---- stage pointwise P,V over the 68x68 region: 3 rounds of quad-tasks ----
  // task i4 -> region row R = i4/18, quad j = i4%18 covering global cols
  // [w0t + 4j - 4, w0t + 4j). Rounds 0,1 fully active (<=1023); round 2:
  // tasks 1024..1223 (200 threads), others clamped+masked.
#define STG_LOAD(r) \
  const int i4r_##r = t + NT_A * (r); \
  const int i4_##r = min(i4r_##r, TOTQ - 1); \
  const int R_##r = i4_##r / NQUAD; \
  const int jq_##r = i4_##r - NQUAD * R_##r; \
  const int gh_##r = h0 + R_##r - 2; \
  const int ghc_##r = min(max(gh_##r, 0), IMG_H - 1); \
  const int g0_##r = w0t + 4 * jq_##r - 4; \
  const int g0c_##r = min(max(g0_##r, 0), IMG_W - 4); \
  const int gb_##r = plane + ghc_##r * IMG_W + g0c_##r; \
  const f4 d4_##r = *(const f4*)(dp + gb_##r); \
  const f4 c4_##r = *(const f4*)(cdp + gb_##r); \
  const f4 g4_##r = *(const f4*)(gxp + gb_##r); \
  const f4 x4_##r = *(const f4*)(cgxp + gb_##r);

#define STG_PROC(r) \
  { \
    const bool act = (i4r_##r < TOTQ); \
    const bool rowv = ((unsigned)gh_##r < (unsigned)IMG_H); \
    float Pq[4], Vq[4]; \
    _Pragma("unroll") \
    for (int q = 0; q < 4; ++q) { \
      const int gw = g0_##r + q; \
      const float m = (rowv & ((unsigned)gw < (unsigned)IMG_W)) ? 1.0f : 0.0f; \
      pointwise_pv(d4_##r[q], c4_##r[q] * m, g4_##r[q], x4_##r[q] * m, gw, \
                   wpc, inv_wp1, Pq[q], Vq[q]); \
    } \
    const int Rb = R_##r * AROWB; \
    const unsigned pm = ((unsigned)(R_##r & 7)) << 4; \
    const int x1 = 16 * jq_##r - 8; \
    const int x2 = 16 * jq_##r; \
    const int o1 = Rb + (int)((unsigned)x1 ^ (x1 < 256 ? pm : 0u)); \
    const int o2 = Rb + (int)((unsigned)x2 ^ (x2 < 256 ? pm : 0u)); \
    if (act & (jq_##r >= 1)) { \
      f2 wp_; wp_[0] = Pq[0]; wp_[1] = Pq[1]; \
      f2 wv_; wv_[0] = Vq[0]; wv_[1] = Vq[1]; \
      *(f2*)(shb + o1) = wp_; \
      *(f2*)(shb + VOFF + o1) = wv_; \
    } \
    if (act & (jq_##r <= 16)) { \
      f2 wp_; wp_[0] = Pq[2]; wp_[1] = Pq[3]; \
      f2 wv_; wv_[0] = Vq[2]; wv_[1] = Vq[3]; \
      *(f2*)(shb + o2) = wp_; \
      *(f2*)(shb + VOFF + o2) = wv_; \
    } \
  }

  STG_LOAD(0)
  STG_LOAD(1)
  STG_PROC(0)
  STG_LOAD(2)
  STG_PROC(1)
  STG_PROC(2)
#undef STG_LOAD
#undef STG_PROC

  // spatial weights for this channel (wave-uniform address -> SGPRs)
  float sww[25];
  #pragma unroll
  for (int k2 = 0; k2 < 25; ++k2) sww[k2] = ws[32 + c * 25 + k2];

  __syncthreads();

  // ---- depthwise 5x5 conv: 512 tasks (64 rows x 8 runs-of-8), 1/thread ----
  {
    const int tau = t;
    const int row = tau >> 3;
    const int c7 = tau & 7;          // run of 8 px starting at col 8*c7
    const int X0 = 32 * c7;          // row-local byte of first quad of window
    const unsigned keep2 = (c7 == 7) ? 0u : 0x70u;  // X0+32==256 -> no swizzle
    float den8[8], nom8[8];
    #pragma unroll
    for (int q = 0; q < 8; ++q) { den8[q] = 0.f; nom8[q] = 0.f; }
    #pragma unroll
    for (int kr = 0; kr < 5; ++kr) {
      const int R = row + kr;
      const int Rb = R * AROWB;
      const unsigned pm = ((unsigned)(R & 7)) << 4;
      const int o0 = Rb + (int)((unsigned)X0 ^ pm);
      const int o1 = Rb + (int)((unsigned)(X0 + 16) ^ pm);
      const int o2 = Rb + (int)((unsigned)(X0 + 32) ^ (pm & keep2));
      const f4 pa = *(const f4*)(shb + o0);
      const f4 pb = *(const f4*)(shb + o1);
      const f4 pc = *(const f4*)(shb + o2);
      const f4 va = *(const f4*)(shb + VOFF + o0);
      const f4 vb = *(const f4*)(shb + VOFF + o1);
      const f4 vc = *(const f4*)(shb + VOFF + o2);
      float pr[12] = {pa[0], pa[1], pa[2], pa[3], pb[0], pb[1], pb[2], pb[3],
                      pc[0], pc[1], pc[2], pc[3]};
      float vr[12] = {va[0], va[1], va[2], va[3], vb[0], vb[1], vb[2], vb[3],
                      vc[0], vc[1], vc[2], vc[3]};
      #pragma unroll
      for (int kc = 0; kc < 5; ++kc) {
        float wv = sww[kr * 5 + kc];
        #pragma unroll
        for (int q = 0; q < 8; ++q) {
          den8[q] = fmaf(wv, pr[kc + q], den8[q]);
          nom8[q] = fmaf(wv, vr[kc + q], nom8[q]);
        }
      }
    }
    // write raw conv sums: D -> first half, N -> second half
    const int gidx = plane + (h0 + row) * IMG_W + w0t + 8 * c7;  // 32B aligned
    float4* sg = (float4*)&out[gidx];
    float4* ug = (float4*)&out[HALF + gidx];
    sg[0] = make_float4(den8[0], den8[1], den8[2], den8[3]);
    sg[1] = make_float4(den8[4], den8[5], den8[6], den8[7]);
    ug[0] = make_float4(nom8[0], nom8[1], nom8[2], nom8[3]);
    ug[1] = make_float4(nom8[4], nom8[5], nom8[6], nom8[7]);
  }
}

// ---------------------------------------------------------------------------
// Kernel B: 1x1 channel normalized conv, in-place on d_out.
// Reads D (first half) and N (second half) for its 256 block-private pixels,
// then overwrites them with gx_out / cgx_out. Barrier between reads & writes.
// Exact compensation for kernelA writing raw D,N:
//   gx_out  = (Σ cw·N) / (Σ cw·D + EPS·Ssw) + bias
//   cgx_out = (Σ cw·D) · (1/Ssw) · (1/Scw)
// ---------------------------------------------------------------------------
__global__ __launch_bounds__(256, 4) void kernelB(
    float* __restrict__ out, const float* __restrict__ ws,
    const float* __restrict__ bias) {
  __shared__ __align__(16) float wlds[NC * NO];  // cwT [c][o]
  __shared__ float blds[NO];

  const int t = threadIdx.x;
  ((float4*)wlds)[t] = ((const float4*)(ws + 832))[t];  // 256*4 = 1024 floats
  if (t < NO) blds[t] = bias[t];
  const float Ssw = ws[1856];
  const float Scw = ws[1857];
  const float epsS = EPSV * Ssw;
  const float scale = rcpf_(Ssw) * rcpf_(Scw);
  __syncthreads();

  const int og = __builtin_amdgcn_readfirstlane(t >> 6);  // wave-uniform
  const int lane = t & 63;
  const int b = blockIdx.y;
  const int hw = blockIdx.x * 256 + lane * 4;
  const int idx0 = b * NC * PLANE + hw;

  float4 accn[8], accd[8];
  #pragma unroll
  for (int o = 0; o < 8; ++o) {
    accn[o] = make_float4(0.f, 0.f, 0.f, 0.f);
    accd[o] = make_float4(0.f, 0.f, 0.f, 0.f);
  }

  #pragma unroll 8
  for (int c = 0; c < NC; ++c) {
    const float4 s4 = *(const float4*)&out[idx0 + c * PLANE];
    const float4 u4 = *(const float4*)&out[HALF + idx0 + c * PLANE];
    const float* w8 = &wlds[c * NO + og * 8];
    #pragma unroll
    for (int o = 0; o < 8; ++o) {
      float wv = w8[o];
      accn[o].x = fmaf(wv, u4.x, accn[o].x);
      accn[o].y = fmaf(wv, u4.y, accn[o].y);
      accn[o].z = fmaf(wv, u4.z, accn[o].z);
      accn[o].w = fmaf(wv, u4.w, accn[o].w);
      accd[o].x = fmaf(wv, s4.x, accd[o].x);
      accd[o].y = fmaf(wv, s4.y, accd[o].y);
      accd[o].z = fmaf(wv, s4.z, accd[o].z);
      accd[o].w = fmaf(wv, s4.w, accd[o].w);
    }
  }

  __syncthreads();  // all reads in block done before any in-place write

  #pragma unroll
  for (int o = 0; o < 8; ++o) {
    int oo = og * 8 + o;
    float bv = blds[oo];
    float4 dn = accd[o];
    float4 g, cg;
    g.x = fmaf(accn[o].x, rcpf_(dn.x + epsS), bv);
    g.y = fmaf(accn[o].y, rcpf_(dn.y + epsS), bv);
    g.z = fmaf(accn[o].z, rcpf_(dn.z + epsS), bv);
    g.w = fmaf(accn[o].w, rcpf_(dn.w + epsS), bv);
    cg.x = dn.x * scale; cg.y = dn.y * scale;
    cg.z = dn.z * scale; cg.w = dn.w * scale;
    int oidx = (b * NO + oo) * PLANE + hw;
    *(float4*)&out[oidx] = g;
    *(float4*)&out[HALF + oidx] = cg;
  }
}

extern "C" void kernel_launch(void* const* d_in, const int* in_sizes, int n_in,
                              void* d_out, int out_size, void* d_ws, size_t ws_size,
                              hipStream_t stream) {
  const float* dp   = (const float*)d_in[0];
  const float* cdp  = (const float*)d_in[1];
  const float* gxp  = (const float*)d_in[2];
  const float* cgxp = (const float*)d_in[3];
  const float* wp   = (const float*)d_in[4];
  const float* sw   = (const float*)d_in[5];
  const float* cw   = (const float*)d_in[6];
  const float* bias = (const float*)d_in[7];
  float* out = (float*)d_out;
  float* ws  = (float*)d_ws;

  weights_kernel<<<1, 256, 0, stream>>>(wp, sw, cw, ws);
  kernelA<<<dim3(16, NC, NB), NT_A, 0, stream>>>(dp, cdp, gxp, cgxp, ws, out);
  kernelB<<<dim3(PLANE / 256, NB), 256, 0, stream>>>(out, ws, bias);
}

// Round 5
// 390.049 us; speedup vs baseline: 1.1799x; 1.0636x over previous
//
#include <hip/hip_runtime.h>
#include <math.h>

// Problem constants (reference: B=8, C=32, O=32, H=256, W=256, K=5, pad=2)
constexpr int IMG_H = 256;
constexpr int IMG_W = 256;
constexpr int NB = 8;
constexpr int NC = 32;
constexpr int NO = 32;
constexpr int PLANE = IMG_H * IMG_W;          // 65536
constexpr int HALF = NB * NC * PLANE;         // 16,777,216 floats (64 MB)

// Fused kernel tiling: block = one (b, 16x32 spatial tile), thread = one pixel,
// channels streamed with double-buffered LDS P,V regions.
constexpr int TW = 16;                        // tile width
constexpr int TH = 32;                        // tile height
constexpr int NT = TW * TH;                   // 512 threads
constexpr int RR = TH + 4;                    // 36 region rows
constexpr int RCF = 24;                       // stored region cols [w0-4, w0+20)
constexpr int RSB = RCF * 4;                  // 96 B row stride (16B aligned)
constexpr int PXB = RR * RSB;                 // 3456 B per array (P or V)
constexpr int BUFB = 2 * PXB;                 // 6912 B per buffer (P then V)
constexpr int NTASK = RR * 12;                // 432 f2 staging tasks
constexpr int TILES = (IMG_W / TW) * (IMG_H / TH);  // 128 tiles per image

#define EPSV 1e-20f

typedef float f4 __attribute__((ext_vector_type(4)));
typedef float f2 __attribute__((ext_vector_type(2)));

__device__ __forceinline__ float rcpf_(float x) { return __builtin_amdgcn_rcpf(x); }
__device__ __forceinline__ float softplusf_(float x) {
  return fmaxf(x, 0.0f) + log1pf(expf(-fabsf(x)));
}

// ws layout (floats): [0..31] wp, [32..831] sw (c-major, 25/ch),
// [832..1855] cwT[c][o] (transposed), [1856] sum(sw), [1857] sum(cw)
__global__ void weights_kernel(const float* __restrict__ wp_raw,
                               const float* __restrict__ sw_raw,
                               const float* __restrict__ cw_raw,
                               float* __restrict__ ws) {
  __shared__ float red[256];
  const int t = threadIdx.x;
  if (t < 32) ws[t] = softplusf_(wp_raw[t]);
  float ssum = 0.f;
  for (int i = t; i < NC * 25; i += 256) {
    float v = softplusf_(sw_raw[i]);
    ws[32 + i] = v;
    ssum += v;
  }
  float csum = 0.f;
  for (int i = t; i < NO * NC; i += 256) {
    float v = softplusf_(cw_raw[i]);
    int o = i >> 5, c = i & 31;
    ws[832 + c * NO + o] = v;  // transposed: [c][o]
    csum += v;
  }
  red[t] = ssum; __syncthreads();
  for (int off = 128; off; off >>= 1) { if (t < off) red[t] += red[t + off]; __syncthreads(); }
  const float S_sw = red[0];
  __syncthreads();
  red[t] = csum; __syncthreads();
  for (int off = 128; off; off >>= 1) { if (t < off) red[t] += red[t + off]; __syncthreads(); }
  if (t == 0) { ws[1856] = S_sw; ws[1857] = red[0]; }
}

// Pointwise gradient-propagation math. Requires cdv/cgv pre-zeroed for
// OOB pixels (then Pv = Vv = 0 follows algebraically, no NaN).
__device__ __forceinline__ void pointwise_pv(
    float dv, float cdv, float gxv, float cgv, int gw,
    float wpc, float inv_wp1, float& Pv, float& Vv) {
  // d_left = d with last col zeroed; d_right = d with first col zeroed
  float dl  = (gw == IMG_W - 1) ? 0.f : dv;
  float cdl = (gw == IMG_W - 1) ? 0.f : cdv;
  float dr  = (gw == 0) ? 0.f : dv;
  float cdr = (gw == 0) ? 0.f : cdv;
  float cfd = cdl * cdr;                                      // cgx_from_ds
  float height = (cdl * dl + cdr * dr) * rcpf_(cdl + cdr + EPSV);
  float gfd = (dr - dl) * 0.5f * rcpf_(height + EPSV);        // gx_from_ds
  float den = fmaf(wpc, cgv, cfd);                            // wp*cgx + cgx_from_ds
  float num = fmaf(wpc * cgv, gxv, cfd * gfd);
  float gprop = num * rcpf_(den + EPSV);
  float cprop = den * inv_wp1;
  Pv = cprop;
  Vv = cprop * gprop;
}

// ---------------------------------------------------------------------------
// Fully fused kernel: pointwise prop + depthwise 5x5 + 1x1 channel conv.
//
// Per block: one (batch b, 16x32 pixel tile). Thread = one pixel, holding 64
// accumulators accN[o], accD[o] (o = 0..31). Channels streamed:
//   for c in 0..31:
//     stage P_c, V_c over the 36x24 halo region into LDS buf[c&1]
//     (f2 global loads, pointwise math; 432 tasks over 512 threads)
//     prefetch channel c+1 inputs into registers   (latency hidden by conv)
//     __syncthreads()
//     D_c = sum_{5x5} sw_c * P,  N_c = sum_{5x5} sw_c * V   (scalar ds_reads,
//       uniformly 2-way banked = free)
//     accD[o] += cw[o][c]*D_c; accN[o] += cw[o][c]*N_c      (rank-1 update)
//   epilogue (folded normalization, exact vs 3-kernel version):
//     gx[o]  = accN[o]/(accD[o] + EPS*Ssw) + bias[o]
//     cgx[o] = accD[o]/(Ssw*Scw)
//
// Eliminates the previous kernelB and the 268 MB D,N HBM round-trip.
// One barrier per channel; write buf[c&1] while others may still read
// buf[(c-1)&1] is race-free (disjoint buffers; see hazard proof in session
// notes: iter c's conv reads are fenced from iter c+2's writes by iter c+1's
// barrier).
// LDS 13,824 B. 64 static-indexed accumulator VGPRs; bounds(512,4) caps VGPR
// at 128 (no squeeze expected; R2 taught us never to starve the pipeline).
// ---------------------------------------------------------------------------
__global__ __launch_bounds__(NT, 4) void fused_kernel(
    const float* __restrict__ dp, const float* __restrict__ cdp,
    const float* __restrict__ gxp, const float* __restrict__ cgxp,
    const float* __restrict__ ws, const float* __restrict__ bias,
    float* __restrict__ out) {
  __shared__ __align__(16) char shb[2 * BUFB];  // 13,824 B

  const int t = threadIdx.x;

  // XCD-aware swizzle: 1024 blocks, 8 XCDs -> XCD k owns image k (tiles in
  // row-major order => horizontal halo neighbors are temporally adjacent on
  // the same L2).
  const int wg = blockIdx.x + blockIdx.y * gridDim.x;   // 0..1023
  const int virt = (wg & 7) * TILES + (wg >> 3);
  const int b = virt >> 7;                              // /TILES (128)
  const int tile = virt & (TILES - 1);
  const int tx = tile & 15, ty = tile >> 4;             // 16 x 8 tile grid
  const int w0 = tx * TW, h0 = ty * TH;

  const float Ssw = ws[1856], Scw = ws[1857];
  const float epsS = EPSV * Ssw;
  const float oscale = rcpf_(Ssw) * rcpf_(Scw);

  // ---- staging task geometry (fixed per thread) ----
  // task ti -> region row R = ti/12, f2 half-quad hq = ti%12 covering global
  // cols g0 = w0-4+2*hq, g0+1. Stored at region bytes R*96 + 8*hq.
  const bool tact = t < NTASK;
  const int R = min(t, NTASK - 1) / 12;
  const int hq = min(t, NTASK - 1) - R * 12;
  const int gh = h0 + R - 2;
  const int ghc = min(max(gh, 0), IMG_H - 1);
  const int g0 = w0 - 4 + 2 * hq;
  const int g0c = min(max(g0, 0), IMG_W - 2);           // even => 8B aligned
  const int goff = ghc * IMG_W + g0c;                   // within-plane offset
  const bool rowv = (unsigned)gh < (unsigned)IMG_H;
  const float m0 = (rowv & ((unsigned)g0 < (unsigned)IMG_W)) ? 1.f : 0.f;
  const float m1 = (rowv & ((unsigned)(g0 + 1) < (unsigned)IMG_W)) ? 1.f : 0.f;
  const int wb = R * RSB + hq * 8;                      // LDS write byte

  // ---- conv geometry ----
  const int x = t & (TW - 1);
  const int r = t >> 4;                                 // 0..31
  const int cvb = r * RSB + (x + 2) * 4;                // window base byte
  const int pixoff = (h0 + r) * IMG_W + (w0 + x);

  const int planebase = b * NC * PLANE;

  float accN[32], accD[32];
  #pragma unroll
  for (int o = 0; o < 32; ++o) { accN[o] = 0.f; accD[o] = 0.f; }

  // prologue: load channel 0 inputs
  f2 vd, vc, vg, vx;
  if (tact) {
    vd = *(const f2*)(dp + planebase + goff);
    vc = *(const f2*)(cdp + planebase + goff);
    vg = *(const f2*)(gxp + planebase + goff);
    vx = *(const f2*)(cgxp + planebase + goff);
  }

  #pragma unroll 1
  for (int c = 0; c < NC; ++c) {
    const int bsel = (c & 1) * BUFB;
    const float wpc = ws[c];
    const float inv_wp1 = rcpf_(wpc + 1.0f);

    // pointwise + LDS write for channel c
    if (tact) {
      float P0, V0, P1, V1;
      pointwise_pv(vd[0], vc[0] * m0, vg[0], vx[0] * m0, g0,
                   wpc, inv_wp1, P0, V0);
      pointwise_pv(vd[1], vc[1] * m1, vg[1], vx[1] * m1, g0 + 1,
                   wpc, inv_wp1, P1, V1);
      f2 Pw; Pw[0] = P0; Pw[1] = P1;
      f2 Vw; Vw[0] = V0; Vw[1] = V1;
      *(f2*)(shb + bsel + wb) = Pw;
      *(f2*)(shb + bsel + PXB + wb) = Vw;
    }

    // prefetch channel c+1 (consumed next iteration; latency hidden by conv)
    if ((c + 1 < NC) & tact) {
      const int pb = planebase + (c + 1) * PLANE + goff;
      vd = *(const f2*)(dp + pb);
      vc = *(const f2*)(cdp + pb);
      vg = *(const f2*)(gxp + pb);
      vx = *(const f2*)(cgxp + pb);
    }

    __syncthreads();  // buf[c&1] (P_c, V_c) complete

    // depthwise 5x5 at this thread's pixel
    const char* bp = shb + bsel + cvb;
    const float* swc = ws + 32 + c * 25;
    float Dc = 0.f, Nc = 0.f;
    #pragma unroll
    for (int kr = 0; kr < 5; ++kr) {
      #pragma unroll
      for (int kc = 0; kc < 5; ++kc) {
        const float wv = swc[kr * 5 + kc];
        const float pv = *(const float*)(bp + kr * RSB + kc * 4);
        const float vv = *(const float*)(bp + PXB + kr * RSB + kc * 4);
        Dc = fmaf(wv, pv, Dc);
        Nc = fmaf(wv, vv, Nc);
      }
    }

    // rank-1 update of the 1x1-conv accumulators
    const float* cwc = ws + 832 + c * NO;
    #pragma unroll
    for (int o = 0; o < 32; ++o) {
      const float wv = cwc[o];
      accD[o] = fmaf(wv, Dc, accD[o]);
      accN[o] = fmaf(wv, Nc, accN[o]);
    }
    // no second barrier needed: next iter writes the other buffer; writes to
    // THIS buffer happen two iterations later, fenced by the next barrier.
  }

  // epilogue: folded normalization + store
  const int ob = b * NO * PLANE + pixoff;
  #pragma unroll
  for (int o = 0; o < 32; ++o) {
    const float g = fmaf(accN[o], rcpf_(accD[o] + epsS), bias[o]);
    const float cg = accD[o] * oscale;
    out[ob + o * PLANE] = g;
    out[HALF + ob + o * PLANE] = cg;
  }
}

extern "C" void kernel_launch(void* const* d_in, const int* in_sizes, int n_in,
                              void* d_out, int out_size, void* d_ws, size_t ws_size,
                              hipStream_t stream) {
  const float* dp   = (const float*)d_in[0];
  const float* cdp  = (const float*)d_in[1];
  const float* gxp  = (const float*)d_in[2];
  const float* cgxp = (const float*)d_in[3];
  const float* wp   = (const float*)d_in[4];
  const float* sw   = (const float*)d_in[5];
  const float* cw   = (const float*)d_in[6];
  const float* bias = (const float*)d_in[7];
  float* out = (float*)d_out;
  float* ws  = (float*)d_ws;

  weights_kernel<<<1, 256, 0, stream>>>(wp, sw, cw, ws);
  fused_kernel<<<dim3(TILES, NB), NT, 0, stream>>>(dp, cdp, gxp, cgxp, ws,
                                                   bias, out);
}